// Round 1
// baseline (798.465 us; speedup 1.0000x reference)
//
#include <hip/hip_runtime.h>
#include <math.h>

#define NN 4096
#define TT 32
#define FF 7
#define HH 64
#define NHEAD 8
#define DOUT 8

__device__ __forceinline__ float sigm(float x){
  x = fminf(fmaxf(x, -30.f), 30.f);
  return 1.f / (1.f + __expf(-x));
}
__device__ __forceinline__ float tanh_fast(float x){
  x = fminf(fmaxf(x, -15.f), 15.f);
  float e = __expf(2.f*x);
  return (e - 1.f) / (e + 1.f);
}

// ---------------- K0: transpose small 64x64 weights to k-major ----------------
__global__ void k0_prep(const float* __restrict__ pw, const float* __restrict__ msw,
                        const float* __restrict__ mpw, const float* __restrict__ sw1,
                        float* __restrict__ wtproj, float* __restrict__ wtself,
                        float* __restrict__ wtpos, float* __restrict__ wtsem)
{
  int tid = threadIdx.x + blockIdx.x*blockDim.x;
  if (tid < 4096){
    int d = tid >> 6, k = tid & 63;
    wtproj[k*64+d] = pw[tid];
    wtself[k*64+d] = msw[tid];
    wtpos[k*64+d]  = mpw[tid];
    wtsem[k*64+d]  = sw1[tid];
  }
}

// ---------------- K1: GRU encoder, 8 nodes/block, 32 lanes/node ----------------
__global__ __launch_bounds__(256, 2) void k1_gru(
    const float* __restrict__ x,      // [N][T][F]
    const float* __restrict__ Wih,    // [192][7]
    const float* __restrict__ Whh,    // [192][64]
    const float* __restrict__ bih, const float* __restrict__ bhh,
    float* __restrict__ hout)         // [N][64]
{
  __shared__ float s_whh[16][192][4];   // [k4][g][4 k-pack]  48KB
  __shared__ float s_wih[192*7];        // packed, stride 7 (conflict-free: gcd(7,32)=1)
  __shared__ float s_x[8][TT*FF];
  __shared__ float s_b[2][192];
  __shared__ float s_h[8][64];

  int tid = threadIdx.x;
  for (int i = tid; i < 192*64; i += 256){
    int g = i >> 6, k = i & 63;
    s_whh[k>>2][g][k&3] = Whh[i];
  }
  for (int i = tid; i < 192*7; i += 256) s_wih[i] = Wih[i];
  for (int i = tid; i < 192; i += 256){ s_b[0][i] = bih[i]; s_b[1][i] = bhh[i]; }
  int nodebase = blockIdx.x * 8;
  for (int i = tid; i < 8*TT*FF; i += 256)
    s_x[i/(TT*FF)][i%(TT*FF)] = x[nodebase*(TT*FF) + i];

  int node = tid >> 5;   // 0..7 (2 nodes per wave)
  int m = tid & 31;
  s_h[node][m] = 0.f; s_h[node][m+32] = 0.f;
  __syncthreads();

  float hp0 = 0.f, hp1 = 0.f;
  float bhh6[6], bih6[6];
  #pragma unroll
  for (int g6 = 0; g6 < 6; ++g6){ bih6[g6] = s_b[0][m + 32*g6]; bhh6[g6] = s_b[1][m + 32*g6]; }

  for (int t = 0; t < TT; ++t){
    float acc[6];
    #pragma unroll
    for (int g6 = 0; g6 < 6; ++g6) acc[g6] = bhh6[g6];
    #pragma unroll
    for (int k4 = 0; k4 < 16; ++k4){
      float4 h4 = *(const float4*)&s_h[node][k4*4];
      #pragma unroll
      for (int g6 = 0; g6 < 6; ++g6){
        float4 w4 = *(const float4*)&s_whh[k4][m + 32*g6][0];
        acc[g6] += h4.x*w4.x + h4.y*w4.y + h4.z*w4.z + h4.w*w4.w;
      }
    }
    float gx[6];
    const float* xp = &s_x[node][t*FF];
    #pragma unroll
    for (int g6 = 0; g6 < 6; ++g6){
      float a = bih6[g6];
      const float* wp = &s_wih[(m+32*g6)*7];
      #pragma unroll
      for (int f = 0; f < 7; ++f) a += wp[f] * xp[f];
      gx[g6] = a;
    }
    float r0 = sigm(gx[0] + acc[0]);
    float r1 = sigm(gx[1] + acc[1]);
    float z0 = sigm(gx[2] + acc[2]);
    float z1 = sigm(gx[3] + acc[3]);
    float n0 = tanh_fast(gx[4] + r0*acc[4]);
    float n1 = tanh_fast(gx[5] + r1*acc[5]);
    hp0 = (1.f - z0)*n0 + z0*hp0;
    hp1 = (1.f - z1)*n1 + z1*hp1;
    s_h[node][m]    = hp0;   // wave-private region: no __syncthreads needed
    s_h[node][m+32] = hp1;
  }
  hout[(nodebase+node)*64 + m]      = hp0;
  hout[(nodebase+node)*64 + m + 32] = hp1;
}

// ---------------- K2: sup = h@gat_w, f1/f2 head scalars, per-block f1 max ----------------
__global__ __launch_bounds__(256) void k2_sup(
    const float* __restrict__ h, const float* __restrict__ gat_w,
    const float* __restrict__ wu, const float* __restrict__ wv,
    float* __restrict__ sup, float* __restrict__ f1, float* __restrict__ f2,
    float* __restrict__ bmax)
{
  int tid = threadIdx.x;
  int wave = tid >> 6, lane = tid & 63;
  int n = blockIdx.x*4 + wave;
  float hreg = h[n*64 + lane];
  float acc = 0.f;
  #pragma unroll
  for (int k = 0; k < 64; ++k){
    float hk = __shfl(hreg, k, 64);
    acc += hk * gat_w[k*64 + lane];
  }
  sup[n*64 + lane] = acc;
  float p1 = acc * wu[lane];
  float p2 = acc * wv[lane];
  #pragma unroll
  for (int s = 1; s < 8; s <<= 1){
    p1 += __shfl_xor(p1, s, 64);
    p2 += __shfl_xor(p2, s, 64);
  }
  int hh = lane >> 3;
  __shared__ float s_m[4][8];
  if ((lane & 7) == 0){
    f1[n*8 + hh] = p1;
    f2[n*8 + hh] = p2;
    s_m[wave][hh] = p1;
  }
  __syncthreads();
  if (tid < 8){
    float mm = fmaxf(fmaxf(s_m[0][tid], s_m[1][tid]), fmaxf(s_m[2][tid], s_m[3][tid]));
    bmax[blockIdx.x*8 + tid] = mm;
  }
}

__global__ __launch_bounds__(256) void k2b_max(const float* __restrict__ bmax, float* __restrict__ maxf1)
{
  int tid = threadIdx.x;
  int hh = tid & 7, chunk = tid >> 3;   // 32 chunks of 32 blocks
  float m = -1e30f;
  for (int b = chunk*32; b < chunk*32+32; ++b) m = fmaxf(m, bmax[b*8 + hh]);
  __shared__ float sm[256];
  sm[tid] = m;
  __syncthreads();
  if (tid < 8){
    float mm = -1e30f;
    for (int c = 0; c < 32; ++c) mm = fmaxf(mm, sm[c*8 + tid]);
    maxf1[tid] = mm;
  }
}

// ---------------- K3: fused masked-softmax GAT, single pass over adj ----------------
__global__ __launch_bounds__(512) void k3_gat(
    const int* __restrict__ adj, const float* __restrict__ sup,
    const float* __restrict__ f1, const float* __restrict__ f2,
    const float* __restrict__ maxf1, float* __restrict__ posg)
{
  __shared__ unsigned long long s_mask[16][64];   // 16 rows x 4096 bits
  __shared__ float s_mrg[3][16][8][10];
  int tid = threadIdx.x;
  int i0 = blockIdx.x * 16;
  {
    int wave = tid >> 6, lane = tid & 63;
    for (int s = wave; s < 16*64; s += 8){
      int row = s >> 6, strip = s & 63;
      int v = adj[(size_t)(i0+row)*NN + strip*64 + lane];
      unsigned long long msk = __ballot(v != 0);
      if (lane == 0) s_mask[row][strip] = msk;
    }
  }
  __syncthreads();
  int r  = tid & 15;
  int hh = (tid >> 4) & 7;
  int js = tid >> 7;            // 0..3, each covers 1024 j
  float f2v = f2[(i0+r)*8 + hh];
  float lg = maxf1[hh] + f2v;
  lg = lg > 0.f ? lg : 0.2f*lg;
  float M = fmaxf(lg, 0.f);     // per-(row,head) upper bound on reference rowmax
  float sum = 0.f;
  float pos[8];
  #pragma unroll
  for (int o = 0; o < 8; ++o) pos[o] = 0.f;

  for (int w = 0; w < 16; ++w){
    unsigned long long mword = s_mask[r][js*16 + w];
    int jbase = js*1024 + w*64;
    #pragma unroll
    for (int c = 0; c < 64; ++c){
      int j = jbase + c;
      float f1v = f1[j*8 + hh];
      const float4* sp = (const float4*)(sup + j*64 + hh*8);
      float4 sa = sp[0], sb = sp[1];
      float logit = f1v + f2v;
      float lr = logit > 0.f ? logit : 0.2f*logit;
      float p = __expf(lr - M);
      p = ((mword >> c) & 1ull) ? p : 0.f;
      sum += p;
      pos[0] += p*sa.x; pos[1] += p*sa.y; pos[2] += p*sa.z; pos[3] += p*sa.w;
      pos[4] += p*sb.x; pos[5] += p*sb.y; pos[6] += p*sb.z; pos[7] += p*sb.w;
    }
  }
  if (js > 0){
    float* dst = &s_mrg[js-1][r][hh][0];
    dst[0] = sum;
    #pragma unroll
    for (int o = 0; o < 8; ++o) dst[1+o] = pos[o];
  }
  __syncthreads();
  if (js == 0){
    #pragma unroll
    for (int q = 0; q < 3; ++q){
      const float* srcp = &s_mrg[q][r][hh][0];
      sum += srcp[0];
      #pragma unroll
      for (int o = 0; o < 8; ++o) pos[o] += srcp[1+o];
    }
    float inv = 1.f / fmaxf(sum, 1e-10f);
    float* dst = &posg[(size_t)(i0+r)*64 + hh*8];
    #pragma unroll
    for (int o = 0; o < 8; ++o) dst[o] = pos[o]*inv;
  }
}

// ---------------- K4: residual proj + the two MLP channels + PairNorm partials ----------------
__global__ __launch_bounds__(256) void k4_mix(
    const float* __restrict__ h, const float* __restrict__ posg,
    const float* __restrict__ gat_bias, const float* __restrict__ proj_b,
    const float* __restrict__ wtproj, const float* __restrict__ wtself,
    const float* __restrict__ wtpos,
    const float* __restrict__ mlp_self_b, const float* __restrict__ mlp_pos_b,
    float* __restrict__ s0, float* __restrict__ s1, float* __restrict__ part)
{
  int tid = threadIdx.x;
  int wave = tid >> 6, lane = tid & 63;
  int n = blockIdx.x*4 + wave;
  float hreg = h[n*64 + lane];
  float pr = proj_b[lane];
  float se = mlp_self_b[lane];
  #pragma unroll
  for (int k = 0; k < 64; ++k){
    float hk = __shfl(hreg, k, 64);
    pr += hk * wtproj[k*64 + lane];
    se += hk * wtself[k*64 + lane];
  }
  float posf = posg[n*64 + lane] + gat_bias[lane] + pr;
  float s1v = mlp_pos_b[lane];
  #pragma unroll
  for (int k = 0; k < 64; ++k){
    float pk = __shfl(posf, k, 64);
    s1v += pk * wtpos[k*64 + lane];
  }
  s0[n*64+lane] = se;
  s1[n*64+lane] = s1v;

  __shared__ float sb0[4][64];
  __shared__ float sb1[4][64];
  __shared__ float sq[4];
  sb0[wave][lane] = se;
  sb1[wave][lane] = s1v;
  float q = se*se + s1v*s1v;
  #pragma unroll
  for (int s = 1; s < 64; s <<= 1) q += __shfl_xor(q, s, 64);
  if (lane == 0) sq[wave] = q;
  __syncthreads();
  if (tid < 64){
    part[blockIdx.x*130 + tid] = sb0[0][tid]+sb0[1][tid]+sb0[2][tid]+sb0[3][tid];
  } else if (tid < 128){
    int d = tid - 64;
    part[blockIdx.x*130 + 64 + d] = sb1[0][d]+sb1[1][d]+sb1[2][d]+sb1[3][d];
  } else if (tid == 128){
    part[blockIdx.x*130 + 128] = sq[0]+sq[1]+sq[2]+sq[3];
  }
}

// ---------------- K5: PairNorm stats (deterministic 1-block reduce) ----------------
__global__ __launch_bounds__(256) void k5_stats(const float* __restrict__ part, float* __restrict__ stats)
{
  int tid = threadIdx.x;
  __shared__ float s_sq[128];
  __shared__ float s_mu2[128];
  if (tid < 128){
    float a = 0.f;
    for (int b = 0; b < 1024; ++b) a += part[b*130 + tid];
    float mu = a / 4096.f;
    stats[tid] = mu;
    s_mu2[tid] = mu*mu;
  } else {
    int c = tid - 128;
    float a = 0.f;
    for (int b = c*8; b < c*8+8; ++b) a += part[b*130 + 128];
    s_sq[c] = a;
  }
  __syncthreads();
  if (tid == 0){
    float sqs = 0.f, mu2 = 0.f;
    for (int i = 0; i < 128; ++i){ sqs += s_sq[i]; mu2 += s_mu2[i]; }
    float msq = sqs/(4096.f*64.f) - mu2/64.f;
    stats[128] = 1.f / sqrtf(1e-6f + msq);
  }
}

// ---------------- K6: semantic attention + predictor ----------------
__global__ __launch_bounds__(256) void k6_sem(
    const float* __restrict__ s0, const float* __restrict__ s1,
    const float* __restrict__ stats, const float* __restrict__ wtsem,
    const float* __restrict__ sem_b1, const float* __restrict__ sem_w2,
    const float* __restrict__ pred_w, const float* __restrict__ pred_b,
    float* __restrict__ out)
{
  int tid = threadIdx.x;
  int wave = tid >> 6, lane = tid & 63;
  int n = blockIdx.x*4 + wave;
  float rinv = stats[128];
  float a0 = (s0[n*64+lane] - stats[lane]) * rinv;
  float a1 = (s1[n*64+lane] - stats[64+lane]) * rinv;
  float t0 = sem_b1[lane], t1 = t0;
  #pragma unroll
  for (int k = 0; k < 64; ++k){
    float w = wtsem[k*64 + lane];
    t0 += __shfl(a0, k, 64) * w;
    t1 += __shfl(a1, k, 64) * w;
  }
  t0 = tanh_fast(t0); t1 = tanh_fast(t1);
  float w2 = sem_w2[lane];
  float w0 = t0*w2, w1 = t1*w2;
  #pragma unroll
  for (int s = 1; s < 64; s <<= 1){
    w0 += __shfl_xor(w0, s, 64);
    w1 += __shfl_xor(w1, s, 64);
  }
  float mx = fmaxf(w0, w1);
  float e0 = __expf(w0 - mx), e1 = __expf(w1 - mx);
  float denom = e0 + e1 + 1e-10f;
  float b0 = e0/denom, b1 = e1/denom;
  float emb = b0*a0 + b1*a1;
  float pl = emb * pred_w[lane];
  #pragma unroll
  for (int s = 1; s < 64; s <<= 1) pl += __shfl_xor(pl, s, 64);
  if (lane == 0) out[n] = sigm(pl + pred_b[0]);
}

extern "C" void kernel_launch(void* const* d_in, const int* in_sizes, int n_in,
                              void* d_out, int out_size, void* d_ws, size_t ws_size,
                              hipStream_t stream)
{
  (void)in_sizes; (void)n_in; (void)out_size; (void)ws_size;
  const float* x         = (const float*)d_in[0];
  const int*   adj       = (const int*)d_in[1];
  const float* W_ih      = (const float*)d_in[2];
  const float* W_hh      = (const float*)d_in[3];
  const float* b_ih      = (const float*)d_in[4];
  const float* b_hh      = (const float*)d_in[5];
  const float* gat_w     = (const float*)d_in[6];
  const float* gat_wu    = (const float*)d_in[7];
  const float* gat_wv    = (const float*)d_in[8];
  const float* gat_bias  = (const float*)d_in[9];
  const float* proj_w    = (const float*)d_in[10];
  const float* proj_b    = (const float*)d_in[11];
  const float* mlp_self_w= (const float*)d_in[12];
  const float* mlp_self_b= (const float*)d_in[13];
  const float* mlp_pos_w = (const float*)d_in[14];
  const float* mlp_pos_b = (const float*)d_in[15];
  const float* sem_w1    = (const float*)d_in[16];
  const float* sem_b1    = (const float*)d_in[17];
  const float* sem_w2    = (const float*)d_in[18];
  const float* pred_w    = (const float*)d_in[19];
  const float* pred_b    = (const float*)d_in[20];
  float* out = (float*)d_out;
  float* ws  = (float*)d_ws;

  float* h     = ws + 0;         // 262144
  float* sup   = ws + 262144;    // 262144
  float* f1    = ws + 524288;    // 32768
  float* f2    = ws + 557056;    // 32768
  float* posg  = ws + 589824;    // 262144
  float* s0    = ws + 851968;    // 262144
  float* s1    = ws + 1114112;   // 262144
  float* part  = ws + 1376256;   // 1024*130
  float* bmax  = ws + 1509376;   // 1024*8
  float* maxf1 = ws + 1517568;   // 8
  float* stats = ws + 1517576;   // 129
  float* wtproj= ws + 1517712;   // 4096
  float* wtself= wtproj + 4096;
  float* wtpos = wtself + 4096;
  float* wtsem = wtpos  + 4096;

  k0_prep<<<16, 256, 0, stream>>>(proj_w, mlp_self_w, mlp_pos_w, sem_w1,
                                  wtproj, wtself, wtpos, wtsem);
  k1_gru<<<512, 256, 0, stream>>>(x, W_ih, W_hh, b_ih, b_hh, h);
  k2_sup<<<1024, 256, 0, stream>>>(h, gat_w, gat_wu, gat_wv, sup, f1, f2, bmax);
  k2b_max<<<1, 256, 0, stream>>>(bmax, maxf1);
  k3_gat<<<256, 512, 0, stream>>>(adj, sup, f1, f2, maxf1, posg);
  k4_mix<<<1024, 256, 0, stream>>>(h, posg, gat_bias, proj_b, wtproj, wtself, wtpos,
                                   mlp_self_b, mlp_pos_b, s0, s1, part);
  k5_stats<<<1, 256, 0, stream>>>(part, stats);
  k6_sem<<<1024, 256, 0, stream>>>(s0, s1, stats, wtsem, sem_b1, sem_w2, pred_w, pred_b, out);
}

// Round 2
// 516.364 us; speedup vs baseline: 1.5463x; 1.5463x over previous
//
#include <hip/hip_runtime.h>
#include <math.h>

#define NN 4096
#define TT 32
#define FF 7
#define HH 64
#define NHEAD 8
#define DOUT 8

__device__ __forceinline__ float sigm(float x){
  x = fminf(fmaxf(x, -30.f), 30.f);
  return 1.f / (1.f + __expf(-x));
}
__device__ __forceinline__ float tanh_fast(float x){
  x = fminf(fmaxf(x, -15.f), 15.f);
  float e = __expf(2.f*x);
  return (e - 1.f) / (e + 1.f);
}

// ---------------- K0: transpose small 64x64 weights to k-major ----------------
__global__ void k0_prep(const float* __restrict__ pw, const float* __restrict__ msw,
                        const float* __restrict__ mpw, const float* __restrict__ sw1,
                        float* __restrict__ wtproj, float* __restrict__ wtself,
                        float* __restrict__ wtpos, float* __restrict__ wtsem)
{
  int tid = threadIdx.x + blockIdx.x*blockDim.x;
  if (tid < 4096){
    int d = tid >> 6, k = tid & 63;
    wtproj[k*64+d] = pw[tid];
    wtself[k*64+d] = msw[tid];
    wtpos[k*64+d]  = mpw[tid];
    wtsem[k*64+d]  = sw1[tid];
  }
}

// ---------------- K1: GRU encoder ----------------
// 256 blocks x 256 threads. Wave handles 4 nodes; lane l owns gates {l, l+64, l+128}.
// W_hh in LDS, XOR-swizzled so 64-lane row reads (stride 256B) are conflict-free.
// h kept per-lane in regs + mirrored in wave-private LDS rows for broadcast reads.
// Entire 32-step loop is barrier-free.
__global__ __launch_bounds__(256) void k1_gru(
    const float* __restrict__ x,      // [N][T][F]
    const float* __restrict__ Wih,    // [192][7]
    const float* __restrict__ Whh,    // [192][64]
    const float* __restrict__ bih, const float* __restrict__ bhh,
    float* __restrict__ hout)         // [N][64]
{
  __shared__ float s_whh[192*64];     // swizzled, 48KB
  __shared__ float s_h[16][64];       // 4KB
  __shared__ float s_x[4][448];       // per-wave x staging (4 nodes x 16 t x 7 f), 7KB

  int tid = threadIdx.x;
  int lane = tid & 63, wave = tid >> 6;

  for (int i = tid; i < 192*64; i += 256){
    int g = i >> 6, k = i & 63;
    s_whh[g*64 + (k ^ ((g & 7) << 2))] = Whh[i];
  }

  float wr_[7], wz_[7], wn_[7];
  #pragma unroll
  for (int f = 0; f < 7; ++f){
    wr_[f] = Wih[lane*7 + f];
    wz_[f] = Wih[(lane+64)*7 + f];
    wn_[f] = Wih[(lane+128)*7 + f];
  }
  float bir = bih[lane], biz = bih[lane+64], bin_ = bih[lane+128];
  float bhr = bhh[lane], bhz = bhh[lane+64], bhn = bhh[lane+128];

  int nb = blockIdx.x*16 + wave*4;    // first node of this wave
  #pragma unroll
  for (int n = 0; n < 4; ++n) s_h[wave*4+n][lane] = 0.f;
  float hreg[4] = {0.f, 0.f, 0.f, 0.f};
  __syncthreads();                    // only barrier: s_whh staging

  int sw = (lane & 7) << 2;           // word swizzle for this lane's rows
  const float* rowr = s_whh + lane*64;
  const float* rowz = s_whh + (lane+64)*64;
  const float* rown = s_whh + (lane+128)*64;

  for (int half = 0; half < 2; ++half){
    // stage x for this wave's 4 nodes, 16 timesteps (wave-private: no barrier)
    for (int i = lane; i < 448; i += 64){
      int n = i / 112, rem = i - n*112;
      s_x[wave][i] = x[(size_t)(nb + n)*224 + half*112 + rem];
    }
    for (int tt = 0; tt < 16; ++tt){
      float accr[4], accz[4], accn[4];
      #pragma unroll
      for (int n = 0; n < 4; ++n){ accr[n]=0.f; accz[n]=0.f; accn[n]=0.f; }
      #pragma unroll
      for (int k4 = 0; k4 < 16; ++k4){
        int off = (k4*4) ^ sw;
        float4 wr4 = *(const float4*)(rowr + off);
        float4 wz4 = *(const float4*)(rowz + off);
        float4 wn4 = *(const float4*)(rown + off);
        #pragma unroll
        for (int n = 0; n < 4; ++n){
          float4 h4 = *(const float4*)&s_h[wave*4+n][k4*4];   // broadcast read
          accr[n] += wr4.x*h4.x + wr4.y*h4.y + wr4.z*h4.z + wr4.w*h4.w;
          accz[n] += wz4.x*h4.x + wz4.y*h4.y + wz4.z*h4.z + wz4.w*h4.w;
          accn[n] += wn4.x*h4.x + wn4.y*h4.y + wn4.z*h4.z + wn4.w*h4.w;
        }
      }
      #pragma unroll
      for (int n = 0; n < 4; ++n){
        const float* xp = &s_x[wave][n*112 + tt*7];
        float gr = bir, gz = biz, gn = bin_;
        #pragma unroll
        for (int f = 0; f < 7; ++f){
          float xv = xp[f];
          gr += wr_[f]*xv; gz += wz_[f]*xv; gn += wn_[f]*xv;
        }
        float rr = sigm(gr + bhr + accr[n]);
        float zz = sigm(gz + bhz + accz[n]);
        float nn = tanh_fast(gn + rr*(bhn + accn[n]));
        float hn = (1.f - zz)*nn + zz*hreg[n];
        hreg[n] = hn;
        s_h[wave*4+n][lane] = hn;
      }
    }
  }
  #pragma unroll
  for (int n = 0; n < 4; ++n)
    hout[(size_t)(nb+n)*64 + lane] = hreg[n];
}

// ---------------- K2: sup = h@gat_w, f1/f2 head scalars, per-block f1 max ----------------
__global__ __launch_bounds__(256) void k2_sup(
    const float* __restrict__ h, const float* __restrict__ gat_w,
    const float* __restrict__ wu, const float* __restrict__ wv,
    float* __restrict__ sup, float* __restrict__ f1, float* __restrict__ f2,
    float* __restrict__ bmax)
{
  int tid = threadIdx.x;
  int wave = tid >> 6, lane = tid & 63;
  int n = blockIdx.x*4 + wave;
  float hreg = h[n*64 + lane];
  float acc = 0.f;
  #pragma unroll
  for (int k = 0; k < 64; ++k){
    float hk = __shfl(hreg, k, 64);
    acc += hk * gat_w[k*64 + lane];
  }
  sup[n*64 + lane] = acc;
  float p1 = acc * wu[lane];
  float p2 = acc * wv[lane];
  #pragma unroll
  for (int s = 1; s < 8; s <<= 1){
    p1 += __shfl_xor(p1, s, 64);
    p2 += __shfl_xor(p2, s, 64);
  }
  int hh = lane >> 3;
  __shared__ float s_m[4][8];
  if ((lane & 7) == 0){
    f1[n*8 + hh] = p1;
    f2[n*8 + hh] = p2;
    s_m[wave][hh] = p1;
  }
  __syncthreads();
  if (tid < 8){
    float mm = fmaxf(fmaxf(s_m[0][tid], s_m[1][tid]), fmaxf(s_m[2][tid], s_m[3][tid]));
    bmax[blockIdx.x*8 + tid] = mm;
  }
}

__global__ __launch_bounds__(256) void k2b_max(const float* __restrict__ bmax, float* __restrict__ maxf1)
{
  int tid = threadIdx.x;
  int hh = tid & 7, chunk = tid >> 3;   // 32 chunks of 32 blocks
  float m = -1e30f;
  for (int b = chunk*32; b < chunk*32+32; ++b) m = fmaxf(m, bmax[b*8 + hh]);
  __shared__ float sm[256];
  sm[tid] = m;
  __syncthreads();
  if (tid < 8){
    float mm = -1e30f;
    for (int c = 0; c < 32; ++c) mm = fmaxf(mm, sm[c*8 + tid]);
    maxf1[tid] = mm;
  }
}

// ---------------- K3: fused masked-softmax GAT, single pass over adj ----------------
// 512 blocks x 512 threads; 8 rows/block; js (wave) splits j-range 8 ways.
__global__ __launch_bounds__(512) void k3_gat(
    const int* __restrict__ adj, const float* __restrict__ sup,
    const float* __restrict__ f1, const float* __restrict__ f2,
    const float* __restrict__ maxf1, float* __restrict__ posg)
{
  __shared__ unsigned long long s_mask[8][64];   // 8 rows x 4096 bits
  __shared__ float s_mrg[7][8][8][10];
  int tid = threadIdx.x;
  int i0 = blockIdx.x * 8;
  {
    int wave = tid >> 6, lane = tid & 63;
    for (int s = wave; s < 8*64; s += 8){
      int row = s >> 6, strip = s & 63;
      int v = adj[(size_t)(i0+row)*NN + strip*64 + lane];
      unsigned long long msk = __ballot(v != 0);
      if (lane == 0) s_mask[row][strip] = msk;
    }
  }
  __syncthreads();
  int r  = tid & 7;
  int hh = (tid >> 3) & 7;
  int js = tid >> 6;            // 0..7, each covers 512 j
  float f2v = f2[(i0+r)*8 + hh];
  float lg = maxf1[hh] + f2v;
  lg = lg > 0.f ? lg : 0.2f*lg;
  float M = fmaxf(lg, 0.f);     // per-(row,head) upper bound on reference rowmax
  float sum = 0.f;
  float pos[8];
  #pragma unroll
  for (int o = 0; o < 8; ++o) pos[o] = 0.f;

  for (int w = 0; w < 8; ++w){
    unsigned long long mword = s_mask[r][js*8 + w];
    int jbase = js*512 + w*64;
    #pragma unroll
    for (int c = 0; c < 64; ++c){
      int j = jbase + c;
      float f1v = f1[j*8 + hh];
      const float4* sp = (const float4*)(sup + j*64 + hh*8);
      float4 sa = sp[0], sb = sp[1];
      float logit = f1v + f2v;
      float lr = logit > 0.f ? logit : 0.2f*logit;
      float p = __expf(lr - M);
      p = ((mword >> c) & 1ull) ? p : 0.f;
      sum += p;
      pos[0] += p*sa.x; pos[1] += p*sa.y; pos[2] += p*sa.z; pos[3] += p*sa.w;
      pos[4] += p*sb.x; pos[5] += p*sb.y; pos[6] += p*sb.z; pos[7] += p*sb.w;
    }
  }
  if (js > 0){
    float* dst = &s_mrg[js-1][r][hh][0];
    dst[0] = sum;
    #pragma unroll
    for (int o = 0; o < 8; ++o) dst[1+o] = pos[o];
  }
  __syncthreads();
  if (js == 0){
    #pragma unroll
    for (int q = 0; q < 7; ++q){
      const float* srcp = &s_mrg[q][r][hh][0];
      sum += srcp[0];
      #pragma unroll
      for (int o = 0; o < 8; ++o) pos[o] += srcp[1+o];
    }
    float inv = 1.f / fmaxf(sum, 1e-10f);
    float* dst = &posg[(size_t)(i0+r)*64 + hh*8];
    #pragma unroll
    for (int o = 0; o < 8; ++o) dst[o] = pos[o]*inv;
  }
}

// ---------------- K4: residual proj + the two MLP channels + PairNorm partials ----------------
__global__ __launch_bounds__(256) void k4_mix(
    const float* __restrict__ h, const float* __restrict__ posg,
    const float* __restrict__ gat_bias, const float* __restrict__ proj_b,
    const float* __restrict__ wtproj, const float* __restrict__ wtself,
    const float* __restrict__ wtpos,
    const float* __restrict__ mlp_self_b, const float* __restrict__ mlp_pos_b,
    float* __restrict__ s0, float* __restrict__ s1, float* __restrict__ part)
{
  int tid = threadIdx.x;
  int wave = tid >> 6, lane = tid & 63;
  int n = blockIdx.x*4 + wave;
  float hreg = h[n*64 + lane];
  float pr = proj_b[lane];
  float se = mlp_self_b[lane];
  #pragma unroll
  for (int k = 0; k < 64; ++k){
    float hk = __shfl(hreg, k, 64);
    pr += hk * wtproj[k*64 + lane];
    se += hk * wtself[k*64 + lane];
  }
  float posf = posg[n*64 + lane] + gat_bias[lane] + pr;
  float s1v = mlp_pos_b[lane];
  #pragma unroll
  for (int k = 0; k < 64; ++k){
    float pk = __shfl(posf, k, 64);
    s1v += pk * wtpos[k*64 + lane];
  }
  s0[n*64+lane] = se;
  s1[n*64+lane] = s1v;

  __shared__ float sb0[4][64];
  __shared__ float sb1[4][64];
  __shared__ float sq[4];
  sb0[wave][lane] = se;
  sb1[wave][lane] = s1v;
  float q = se*se + s1v*s1v;
  #pragma unroll
  for (int s = 1; s < 64; s <<= 1) q += __shfl_xor(q, s, 64);
  if (lane == 0) sq[wave] = q;
  __syncthreads();
  if (tid < 64){
    part[blockIdx.x*130 + tid] = sb0[0][tid]+sb0[1][tid]+sb0[2][tid]+sb0[3][tid];
  } else if (tid < 128){
    int d = tid - 64;
    part[blockIdx.x*130 + 64 + d] = sb1[0][d]+sb1[1][d]+sb1[2][d]+sb1[3][d];
  } else if (tid == 128){
    part[blockIdx.x*130 + 128] = sq[0]+sq[1]+sq[2]+sq[3];
  }
}

// ---------------- K5: PairNorm stats (1024-thread two-stage reduce) ----------------
__global__ __launch_bounds__(1024) void k5_stats(const float* __restrict__ part, float* __restrict__ stats)
{
  int tid = threadIdx.x;
  __shared__ float s_mu[8][128];
  __shared__ float s_sq[8];
  int c = tid & 127, ch = tid >> 7;
  float a = 0.f;
  for (int b = ch*128; b < ch*128+128; ++b) a += part[b*130 + c];
  s_mu[ch][c] = a;
  if (tid < 8){
    float q = 0.f;
    for (int b = tid*128; b < tid*128+128; ++b) q += part[b*130 + 128];
    s_sq[tid] = q;
  }
  __syncthreads();
  if (tid < 128){
    float m = 0.f;
    #pragma unroll
    for (int j = 0; j < 8; ++j) m += s_mu[j][tid];
    s_mu[0][tid] = m;
    stats[tid] = m / 4096.f;
  }
  __syncthreads();
  if (tid == 0){
    float sq = 0.f;
    #pragma unroll
    for (int j = 0; j < 8; ++j) sq += s_sq[j];
    float mu2 = 0.f;
    for (int i = 0; i < 128; ++i){ float m = s_mu[0][i] / 4096.f; mu2 += m*m; }
    float msq = sq/(4096.f*64.f) - mu2/64.f;
    stats[128] = 1.f / sqrtf(1e-6f + msq);
  }
}

// ---------------- K6: semantic attention + predictor ----------------
__global__ __launch_bounds__(256) void k6_sem(
    const float* __restrict__ s0, const float* __restrict__ s1,
    const float* __restrict__ stats, const float* __restrict__ wtsem,
    const float* __restrict__ sem_b1, const float* __restrict__ sem_w2,
    const float* __restrict__ pred_w, const float* __restrict__ pred_b,
    float* __restrict__ out)
{
  int tid = threadIdx.x;
  int wave = tid >> 6, lane = tid & 63;
  int n = blockIdx.x*4 + wave;
  float rinv = stats[128];
  float a0 = (s0[n*64+lane] - stats[lane]) * rinv;
  float a1 = (s1[n*64+lane] - stats[64+lane]) * rinv;
  float t0 = sem_b1[lane], t1 = t0;
  #pragma unroll
  for (int k = 0; k < 64; ++k){
    float w = wtsem[k*64 + lane];
    t0 += __shfl(a0, k, 64) * w;
    t1 += __shfl(a1, k, 64) * w;
  }
  t0 = tanh_fast(t0); t1 = tanh_fast(t1);
  float w2 = sem_w2[lane];
  float w0 = t0*w2, w1 = t1*w2;
  #pragma unroll
  for (int s = 1; s < 64; s <<= 1){
    w0 += __shfl_xor(w0, s, 64);
    w1 += __shfl_xor(w1, s, 64);
  }
  float mx = fmaxf(w0, w1);
  float e0 = __expf(w0 - mx), e1 = __expf(w1 - mx);
  float denom = e0 + e1 + 1e-10f;
  float b0 = e0/denom, b1 = e1/denom;
  float emb = b0*a0 + b1*a1;
  float pl = emb * pred_w[lane];
  #pragma unroll
  for (int s = 1; s < 64; s <<= 1) pl += __shfl_xor(pl, s, 64);
  if (lane == 0) out[n] = sigm(pl + pred_b[0]);
}

extern "C" void kernel_launch(void* const* d_in, const int* in_sizes, int n_in,
                              void* d_out, int out_size, void* d_ws, size_t ws_size,
                              hipStream_t stream)
{
  (void)in_sizes; (void)n_in; (void)out_size; (void)ws_size;
  const float* x         = (const float*)d_in[0];
  const int*   adj       = (const int*)d_in[1];
  const float* W_ih      = (const float*)d_in[2];
  const float* W_hh      = (const float*)d_in[3];
  const float* b_ih      = (const float*)d_in[4];
  const float* b_hh      = (const float*)d_in[5];
  const float* gat_w     = (const float*)d_in[6];
  const float* gat_wu    = (const float*)d_in[7];
  const float* gat_wv    = (const float*)d_in[8];
  const float* gat_bias  = (const float*)d_in[9];
  const float* proj_w    = (const float*)d_in[10];
  const float* proj_b    = (const float*)d_in[11];
  const float* mlp_self_w= (const float*)d_in[12];
  const float* mlp_self_b= (const float*)d_in[13];
  const float* mlp_pos_w = (const float*)d_in[14];
  const float* mlp_pos_b = (const float*)d_in[15];
  const float* sem_w1    = (const float*)d_in[16];
  const float* sem_b1    = (const float*)d_in[17];
  const float* sem_w2    = (const float*)d_in[18];
  const float* pred_w    = (const float*)d_in[19];
  const float* pred_b    = (const float*)d_in[20];
  float* out = (float*)d_out;
  float* ws  = (float*)d_ws;

  float* h     = ws + 0;         // 262144
  float* sup   = ws + 262144;    // 262144
  float* f1    = ws + 524288;    // 32768
  float* f2    = ws + 557056;    // 32768
  float* posg  = ws + 589824;    // 262144
  float* s0    = ws + 851968;    // 262144
  float* s1    = ws + 1114112;   // 262144
  float* part  = ws + 1376256;   // 1024*130
  float* bmax  = ws + 1509376;   // 1024*8
  float* maxf1 = ws + 1517568;   // 8
  float* stats = ws + 1517576;   // 129
  float* wtproj= ws + 1517712;   // 4096
  float* wtself= wtproj + 4096;
  float* wtpos = wtself + 4096;
  float* wtsem = wtpos  + 4096;

  k0_prep<<<16, 256, 0, stream>>>(proj_w, mlp_self_w, mlp_pos_w, sem_w1,
                                  wtproj, wtself, wtpos, wtsem);
  k1_gru<<<256, 256, 0, stream>>>(x, W_ih, W_hh, b_ih, b_hh, h);
  k2_sup<<<1024, 256, 0, stream>>>(h, gat_w, gat_wu, gat_wv, sup, f1, f2, bmax);
  k2b_max<<<1, 256, 0, stream>>>(bmax, maxf1);
  k3_gat<<<512, 512, 0, stream>>>(adj, sup, f1, f2, maxf1, posg);
  k4_mix<<<1024, 256, 0, stream>>>(h, posg, gat_bias, proj_b, wtproj, wtself, wtpos,
                                   mlp_self_b, mlp_pos_b, s0, s1, part);
  k5_stats<<<1, 1024, 0, stream>>>(part, stats);
  k6_sem<<<1024, 256, 0, stream>>>(s0, s1, stats, wtsem, sem_b1, sem_w2, pred_w, pred_b, out);
}

// Round 3
// 444.985 us; speedup vs baseline: 1.7944x; 1.1604x over previous
//
#include <hip/hip_runtime.h>
#include <math.h>

#define NN 4096
#define TT 32
#define FF 7
#define HH 64
#define NHEAD 8
#define DOUT 8
#define JT 128

__device__ __forceinline__ float sigm(float x){
  x = fminf(fmaxf(x, -30.f), 30.f);
  return 1.f / (1.f + __expf(-x));
}
__device__ __forceinline__ float tanh_fast(float x){
  x = fminf(fmaxf(x, -15.f), 15.f);
  float e = __expf(2.f*x);
  return (e - 1.f) / (e + 1.f);
}

// ---------------- K0: transpose small 64x64 weights to k-major ----------------
__global__ void k0_prep(const float* __restrict__ pw, const float* __restrict__ msw,
                        const float* __restrict__ mpw, const float* __restrict__ sw1,
                        float* __restrict__ wtproj, float* __restrict__ wtself,
                        float* __restrict__ wtpos, float* __restrict__ wtsem)
{
  int tid = threadIdx.x + blockIdx.x*blockDim.x;
  if (tid < 4096){
    int d = tid >> 6, k = tid & 63;
    wtproj[k*64+d] = pw[tid];
    wtself[k*64+d] = msw[tid];
    wtpos[k*64+d]  = mpw[tid];
    wtsem[k*64+d]  = sw1[tid];
  }
}

// ---------------- K1: GRU encoder ----------------
__global__ __launch_bounds__(256) void k1_gru(
    const float* __restrict__ x,      // [N][T][F]
    const float* __restrict__ Wih,    // [192][7]
    const float* __restrict__ Whh,    // [192][64]
    const float* __restrict__ bih, const float* __restrict__ bhh,
    float* __restrict__ hout)         // [N][64]
{
  __shared__ float s_whh[192*64];     // swizzled, 48KB
  __shared__ float s_h[16][64];       // 4KB
  __shared__ float s_x[4][448];       // per-wave x staging (4 nodes x 16 t x 7 f), 7KB

  int tid = threadIdx.x;
  int lane = tid & 63, wave = tid >> 6;

  for (int i = tid; i < 192*64; i += 256){
    int g = i >> 6, k = i & 63;
    s_whh[g*64 + (k ^ ((g & 7) << 2))] = Whh[i];
  }

  float wr_[7], wz_[7], wn_[7];
  #pragma unroll
  for (int f = 0; f < 7; ++f){
    wr_[f] = Wih[lane*7 + f];
    wz_[f] = Wih[(lane+64)*7 + f];
    wn_[f] = Wih[(lane+128)*7 + f];
  }
  float bir = bih[lane], biz = bih[lane+64], bin_ = bih[lane+128];
  float bhr = bhh[lane], bhz = bhh[lane+64], bhn = bhh[lane+128];

  int nb = blockIdx.x*16 + wave*4;    // first node of this wave
  #pragma unroll
  for (int n = 0; n < 4; ++n) s_h[wave*4+n][lane] = 0.f;
  float hreg[4] = {0.f, 0.f, 0.f, 0.f};
  __syncthreads();                    // only barrier: s_whh staging

  int sw = (lane & 7) << 2;           // word swizzle for this lane's rows
  const float* rowr = s_whh + lane*64;
  const float* rowz = s_whh + (lane+64)*64;
  const float* rown = s_whh + (lane+128)*64;

  for (int half = 0; half < 2; ++half){
    // stage x for this wave's 4 nodes, 16 timesteps (wave-private: no barrier)
    for (int i = lane; i < 448; i += 64){
      int n = i / 112, rem = i - n*112;
      s_x[wave][i] = x[(size_t)(nb + n)*224 + half*112 + rem];
    }
    for (int tt = 0; tt < 16; ++tt){
      float accr[4], accz[4], accn[4];
      #pragma unroll
      for (int n = 0; n < 4; ++n){ accr[n]=0.f; accz[n]=0.f; accn[n]=0.f; }
      #pragma unroll
      for (int k4 = 0; k4 < 16; ++k4){
        int off = (k4*4) ^ sw;
        float4 wr4 = *(const float4*)(rowr + off);
        float4 wz4 = *(const float4*)(rowz + off);
        float4 wn4 = *(const float4*)(rown + off);
        #pragma unroll
        for (int n = 0; n < 4; ++n){
          float4 h4 = *(const float4*)&s_h[wave*4+n][k4*4];   // broadcast read
          accr[n] += wr4.x*h4.x + wr4.y*h4.y + wr4.z*h4.z + wr4.w*h4.w;
          accz[n] += wz4.x*h4.x + wz4.y*h4.y + wz4.z*h4.z + wz4.w*h4.w;
          accn[n] += wn4.x*h4.x + wn4.y*h4.y + wn4.z*h4.z + wn4.w*h4.w;
        }
      }
      #pragma unroll
      for (int n = 0; n < 4; ++n){
        const float* xp = &s_x[wave][n*112 + tt*7];
        float gr = bir, gz = biz, gn = bin_;
        #pragma unroll
        for (int f = 0; f < 7; ++f){
          float xv = xp[f];
          gr += wr_[f]*xv; gz += wz_[f]*xv; gn += wn_[f]*xv;
        }
        float rr = sigm(gr + bhr + accr[n]);
        float zz = sigm(gz + bhz + accz[n]);
        float nn = tanh_fast(gn + rr*(bhn + accn[n]));
        float hn = (1.f - zz)*nn + zz*hreg[n];
        hreg[n] = hn;
        s_h[wave*4+n][lane] = hn;
      }
    }
  }
  #pragma unroll
  for (int n = 0; n < 4; ++n)
    hout[(size_t)(nb+n)*64 + lane] = hreg[n];
}

// ---------------- K2: sup = h@gat_w, f1/f2 head scalars, per-block f1 max ----------------
__global__ __launch_bounds__(256) void k2_sup(
    const float* __restrict__ h, const float* __restrict__ gat_w,
    const float* __restrict__ wu, const float* __restrict__ wv,
    float* __restrict__ sup, float* __restrict__ f1, float* __restrict__ f2,
    float* __restrict__ bmax)
{
  int tid = threadIdx.x;
  int wave = tid >> 6, lane = tid & 63;
  int n = blockIdx.x*4 + wave;
  float hreg = h[n*64 + lane];
  float acc = 0.f;
  #pragma unroll
  for (int k = 0; k < 64; ++k){
    float hk = __shfl(hreg, k, 64);
    acc += hk * gat_w[k*64 + lane];
  }
  sup[n*64 + lane] = acc;
  float p1 = acc * wu[lane];
  float p2 = acc * wv[lane];
  #pragma unroll
  for (int s = 1; s < 8; s <<= 1){
    p1 += __shfl_xor(p1, s, 64);
    p2 += __shfl_xor(p2, s, 64);
  }
  int hh = lane >> 3;
  __shared__ float s_m[4][8];
  if ((lane & 7) == 0){
    f1[n*8 + hh] = p1;
    f2[n*8 + hh] = p2;
    s_m[wave][hh] = p1;
  }
  __syncthreads();
  if (tid < 8){
    float mm = fmaxf(fmaxf(s_m[0][tid], s_m[1][tid]), fmaxf(s_m[2][tid], s_m[3][tid]));
    bmax[blockIdx.x*8 + tid] = mm;
  }
}

__global__ __launch_bounds__(256) void k2b_max(const float* __restrict__ bmax, float* __restrict__ maxf1)
{
  int tid = threadIdx.x;
  int hh = tid & 7, chunk = tid >> 3;   // 32 chunks of 32 blocks
  float m = -1e30f;
  for (int b = chunk*32; b < chunk*32+32; ++b) m = fmaxf(m, bmax[b*8 + hh]);
  __shared__ float sm[256];
  sm[tid] = m;
  __syncthreads();
  if (tid < 8){
    float mm = -1e30f;
    for (int c = 0; c < 32; ++c) mm = fmaxf(mm, sm[c*8 + tid]);
    maxf1[tid] = mm;
  }
}

// ---------------- K3: fused masked-softmax GAT, LDS-tiled with register prefetch ----------------
// 512 blocks x 512 threads; 8 rows/block; lane = (r, hh), wave = js over j-subrange.
// j tiled by 128: sup tile (32KB) + f1 tile (4KB) staged in LDS; next tile prefetched
// into registers while current tile computes (global latency hidden under VALU).
__global__ __launch_bounds__(512) void k3_gat(
    const int* __restrict__ adj, const float* __restrict__ sup,
    const float* __restrict__ f1, const float* __restrict__ f2,
    const float* __restrict__ maxf1, float* __restrict__ posg)
{
  __shared__ unsigned long long s_mask[8][65];   // pad 65: row-lanes hit distinct banks
  __shared__ float s_sup[JT*64];                 // 32 KB
  __shared__ float s_f1[JT*8];                   // 4 KB
  __shared__ float s_mrg[7][8][8][10];

  int tid = threadIdx.x;
  int i0 = blockIdx.x * 8;
  int lane = tid & 63, wave = tid >> 6;

  // ballot-pack adjacency rows to bitmasks
  for (int s = wave; s < 8*64; s += 8){
    int row = s >> 6, strip = s & 63;
    int v = adj[(size_t)(i0+row)*NN + strip*64 + lane];
    unsigned long long msk = __ballot(v != 0);
    if (lane == 0) s_mask[row][strip] = msk;
  }

  int r  = tid & 7;
  int hh = (tid >> 3) & 7;
  int js = wave;                // 0..7
  float f2v = f2[(i0+r)*8 + hh];
  float lg = maxf1[hh] + f2v;
  lg = lg > 0.f ? lg : 0.2f*lg;
  float M = fmaxf(lg, 0.f);     // per-(row,head) upper bound on reference rowmax
  float sum = 0.f;
  float pos[8];
  #pragma unroll
  for (int o = 0; o < 8; ++o) pos[o] = 0.f;

  // register prefetch pipeline
  float4 rs[4]; float2 rf;
  {
    const float4* gs = (const float4*)sup;
    #pragma unroll
    for (int p = 0; p < 4; ++p) rs[p] = gs[tid + p*512];
    rf = ((const float2*)f1)[tid];
  }

  for (int t = 0; t < NN/JT; ++t){
    __syncthreads();                       // everyone done reading previous tile
    {
      float4* ds = (float4*)s_sup;
      #pragma unroll
      for (int p = 0; p < 4; ++p) ds[tid + p*512] = rs[p];
      ((float2*)s_f1)[tid] = rf;
    }
    if (t + 1 < NN/JT){
      int j0 = (t+1)*JT;
      const float4* gs = (const float4*)(sup + (size_t)j0*64);
      #pragma unroll
      for (int p = 0; p < 4; ++p) rs[p] = gs[tid + p*512];
      rf = ((const float2*)(f1 + (size_t)j0*8))[tid];
    }
    __syncthreads();                       // tile visible

    unsigned long long mword = s_mask[r][t*2 + (js>>2)];
    unsigned mw = (unsigned)((mword >> ((js&3)*16)) & 0xffffULL);
    int jl0 = js*16;
    #pragma unroll
    for (int c = 0; c < 16; ++c){
      int jl = jl0 + c;
      float f1v = s_f1[jl*8 + hh];
      const float4* sp = (const float4*)(s_sup + jl*64 + hh*8);
      float4 sa = sp[0], sb = sp[1];
      float logit = f1v + f2v;
      float lr = fmaxf(logit, 0.2f*logit);
      float p = __expf(lr - M);
      p = ((mw >> c) & 1u) ? p : 0.f;
      sum += p;
      pos[0] += p*sa.x; pos[1] += p*sa.y; pos[2] += p*sa.z; pos[3] += p*sa.w;
      pos[4] += p*sb.x; pos[5] += p*sb.y; pos[6] += p*sb.z; pos[7] += p*sb.w;
    }
  }

  if (js > 0){
    float* dst = &s_mrg[js-1][r][hh][0];
    dst[0] = sum;
    #pragma unroll
    for (int o = 0; o < 8; ++o) dst[1+o] = pos[o];
  }
  __syncthreads();
  if (js == 0){
    #pragma unroll
    for (int q = 0; q < 7; ++q){
      const float* srcp = &s_mrg[q][r][hh][0];
      sum += srcp[0];
      #pragma unroll
      for (int o = 0; o < 8; ++o) pos[o] += srcp[1+o];
    }
    float inv = 1.f / fmaxf(sum, 1e-10f);
    float* dst = &posg[(size_t)(i0+r)*64 + hh*8];
    #pragma unroll
    for (int o = 0; o < 8; ++o) dst[o] = pos[o]*inv;
  }
}

// ---------------- K4: residual proj + the two MLP channels + PairNorm partials ----------------
__global__ __launch_bounds__(256) void k4_mix(
    const float* __restrict__ h, const float* __restrict__ posg,
    const float* __restrict__ gat_bias, const float* __restrict__ proj_b,
    const float* __restrict__ wtproj, const float* __restrict__ wtself,
    const float* __restrict__ wtpos,
    const float* __restrict__ mlp_self_b, const float* __restrict__ mlp_pos_b,
    float* __restrict__ s0, float* __restrict__ s1, float* __restrict__ part)
{
  int tid = threadIdx.x;
  int wave = tid >> 6, lane = tid & 63;
  int n = blockIdx.x*4 + wave;
  float hreg = h[n*64 + lane];
  float pr = proj_b[lane];
  float se = mlp_self_b[lane];
  #pragma unroll
  for (int k = 0; k < 64; ++k){
    float hk = __shfl(hreg, k, 64);
    pr += hk * wtproj[k*64 + lane];
    se += hk * wtself[k*64 + lane];
  }
  float posf = posg[n*64 + lane] + gat_bias[lane] + pr;
  float s1v = mlp_pos_b[lane];
  #pragma unroll
  for (int k = 0; k < 64; ++k){
    float pk = __shfl(posf, k, 64);
    s1v += pk * wtpos[k*64 + lane];
  }
  s0[n*64+lane] = se;
  s1[n*64+lane] = s1v;

  __shared__ float sb0[4][64];
  __shared__ float sb1[4][64];
  __shared__ float sq[4];
  sb0[wave][lane] = se;
  sb1[wave][lane] = s1v;
  float q = se*se + s1v*s1v;
  #pragma unroll
  for (int s = 1; s < 64; s <<= 1) q += __shfl_xor(q, s, 64);
  if (lane == 0) sq[wave] = q;
  __syncthreads();
  if (tid < 64){
    part[blockIdx.x*130 + tid] = sb0[0][tid]+sb0[1][tid]+sb0[2][tid]+sb0[3][tid];
  } else if (tid < 128){
    int d = tid - 64;
    part[blockIdx.x*130 + 64 + d] = sb1[0][d]+sb1[1][d]+sb1[2][d]+sb1[3][d];
  } else if (tid == 128){
    part[blockIdx.x*130 + 128] = sq[0]+sq[1]+sq[2]+sq[3];
  }
}

// ---------------- K5: PairNorm stats (1024-thread two-stage reduce) ----------------
__global__ __launch_bounds__(1024) void k5_stats(const float* __restrict__ part, float* __restrict__ stats)
{
  int tid = threadIdx.x;
  __shared__ float s_mu[8][128];
  __shared__ float s_sq[8];
  int c = tid & 127, ch = tid >> 7;
  float a = 0.f;
  for (int b = ch*128; b < ch*128+128; ++b) a += part[b*130 + c];
  s_mu[ch][c] = a;
  if (tid < 8){
    float q = 0.f;
    for (int b = tid*128; b < tid*128+128; ++b) q += part[b*130 + 128];
    s_sq[tid] = q;
  }
  __syncthreads();
  if (tid < 128){
    float m = 0.f;
    #pragma unroll
    for (int j = 0; j < 8; ++j) m += s_mu[j][tid];
    s_mu[0][tid] = m;
    stats[tid] = m / 4096.f;
  }
  __syncthreads();
  if (tid == 0){
    float sq = 0.f;
    #pragma unroll
    for (int j = 0; j < 8; ++j) sq += s_sq[j];
    float mu2 = 0.f;
    for (int i = 0; i < 128; ++i){ float m = s_mu[0][i] / 4096.f; mu2 += m*m; }
    float msq = sq/(4096.f*64.f) - mu2/64.f;
    stats[128] = 1.f / sqrtf(1e-6f + msq);
  }
}

// ---------------- K6: semantic attention + predictor ----------------
__global__ __launch_bounds__(256) void k6_sem(
    const float* __restrict__ s0, const float* __restrict__ s1,
    const float* __restrict__ stats, const float* __restrict__ wtsem,
    const float* __restrict__ sem_b1, const float* __restrict__ sem_w2,
    const float* __restrict__ pred_w, const float* __restrict__ pred_b,
    float* __restrict__ out)
{
  int tid = threadIdx.x;
  int wave = tid >> 6, lane = tid & 63;
  int n = blockIdx.x*4 + wave;
  float rinv = stats[128];
  float a0 = (s0[n*64+lane] - stats[lane]) * rinv;
  float a1 = (s1[n*64+lane] - stats[64+lane]) * rinv;
  float t0 = sem_b1[lane], t1 = t0;
  #pragma unroll
  for (int k = 0; k < 64; ++k){
    float w = wtsem[k*64 + lane];
    t0 += __shfl(a0, k, 64) * w;
    t1 += __shfl(a1, k, 64) * w;
  }
  t0 = tanh_fast(t0); t1 = tanh_fast(t1);
  float w2 = sem_w2[lane];
  float w0 = t0*w2, w1 = t1*w2;
  #pragma unroll
  for (int s = 1; s < 64; s <<= 1){
    w0 += __shfl_xor(w0, s, 64);
    w1 += __shfl_xor(w1, s, 64);
  }
  float mx = fmaxf(w0, w1);
  float e0 = __expf(w0 - mx), e1 = __expf(w1 - mx);
  float denom = e0 + e1 + 1e-10f;
  float b0 = e0/denom, b1 = e1/denom;
  float emb = b0*a0 + b1*a1;
  float pl = emb * pred_w[lane];
  #pragma unroll
  for (int s = 1; s < 64; s <<= 1) pl += __shfl_xor(pl, s, 64);
  if (lane == 0) out[n] = sigm(pl + pred_b[0]);
}

extern "C" void kernel_launch(void* const* d_in, const int* in_sizes, int n_in,
                              void* d_out, int out_size, void* d_ws, size_t ws_size,
                              hipStream_t stream)
{
  (void)in_sizes; (void)n_in; (void)out_size; (void)ws_size;
  const float* x         = (const float*)d_in[0];
  const int*   adj       = (const int*)d_in[1];
  const float* W_ih      = (const float*)d_in[2];
  const float* W_hh      = (const float*)d_in[3];
  const float* b_ih      = (const float*)d_in[4];
  const float* b_hh      = (const float*)d_in[5];
  const float* gat_w     = (const float*)d_in[6];
  const float* gat_wu    = (const float*)d_in[7];
  const float* gat_wv    = (const float*)d_in[8];
  const float* gat_bias  = (const float*)d_in[9];
  const float* proj_w    = (const float*)d_in[10];
  const float* proj_b    = (const float*)d_in[11];
  const float* mlp_self_w= (const float*)d_in[12];
  const float* mlp_self_b= (const float*)d_in[13];
  const float* mlp_pos_w = (const float*)d_in[14];
  const float* mlp_pos_b = (const float*)d_in[15];
  const float* sem_w1    = (const float*)d_in[16];
  const float* sem_b1    = (const float*)d_in[17];
  const float* sem_w2    = (const float*)d_in[18];
  const float* pred_w    = (const float*)d_in[19];
  const float* pred_b    = (const float*)d_in[20];
  float* out = (float*)d_out;
  float* ws  = (float*)d_ws;

  float* h     = ws + 0;         // 262144
  float* sup   = ws + 262144;    // 262144
  float* f1    = ws + 524288;    // 32768
  float* f2    = ws + 557056;    // 32768
  float* posg  = ws + 589824;    // 262144
  float* s0    = ws + 851968;    // 262144
  float* s1    = ws + 1114112;   // 262144
  float* part  = ws + 1376256;   // 1024*130
  float* bmax  = ws + 1509376;   // 1024*8
  float* maxf1 = ws + 1517568;   // 8
  float* stats = ws + 1517576;   // 129
  float* wtproj= ws + 1517712;   // 4096
  float* wtself= wtproj + 4096;
  float* wtpos = wtself + 4096;
  float* wtsem = wtpos  + 4096;

  k0_prep<<<16, 256, 0, stream>>>(proj_w, mlp_self_w, mlp_pos_w, sem_w1,
                                  wtproj, wtself, wtpos, wtsem);
  k1_gru<<<256, 256, 0, stream>>>(x, W_ih, W_hh, b_ih, b_hh, h);
  k2_sup<<<1024, 256, 0, stream>>>(h, gat_w, gat_wu, gat_wv, sup, f1, f2, bmax);
  k2b_max<<<1, 256, 0, stream>>>(bmax, maxf1);
  k3_gat<<<512, 512, 0, stream>>>(adj, sup, f1, f2, maxf1, posg);
  k4_mix<<<1024, 256, 0, stream>>>(h, posg, gat_bias, proj_b, wtproj, wtself, wtpos,
                                   mlp_self_b, mlp_pos_b, s0, s1, part);
  k5_stats<<<1, 1024, 0, stream>>>(part, stats);
  k6_sem<<<1024, 256, 0, stream>>>(s0, s1, stats, wtsem, sem_b1, sem_w2, pred_w, pred_b, out);
}